// Round 1
// baseline (144.069 us; speedup 1.0000x reference)
//
#include <hip/hip_runtime.h>
#include <math.h>

// EquivariantWSSHead: V=100000 vertices, E=1600000 edges, C0=C1=16.
//
// R1..R12: zero-global-atomic bucket binning; bf16 table (3.2MB) + 8B
//   payload; LDS tuple-sort so scatter reads AND writes are sequential.
// R13 (fused): per-kernel time is real; dur_us has ~70us harness floor
//   (256MB workspace poison-fill = 42us/iter, visible as top dispatches).
// R14: bin-major line-aligned payload; bucket invariant was 6.4M FLOAT
//   LDS atomics (CAS-loop lowering).
// R15: fixed-point INT accumulate (scale 2^17) -> native ds_add_u32.
// R16 (this round):
//   a) bucket: pack (m0+bias, mv1) and (mv2+bias, count) into TWO u64
//      LDS atomics per edge (ds_add_u64) instead of four ds_add_u32.
//      Bias 2^22 keeps the low field non-negative so it never carries
//      into the high field (per-copy adds <= deg <= ~60 << 512 headroom);
//      bias removed at finalize via the per-copy count in word2's high.
//   b) precompute+count fused into one kernel (independent work, was
//      serialized on the stream).
//   c) scatter: __sinf/__cosf (native v_sin/v_cos; args in [0,2pi),
//      error ~1e-6 << bf16 payload error).

#define VB 256           // vertices per bucket
#define VB_SHIFT 8
#define MAXNB 400        // NB = ceil(V/256) = 391 for V=100000
#define CHUNK 3125       // edges per chunk
#define NCHUNK 512       // chunks (E/CHUNK)
#define BIGT 1024
#define FIXS 131072.0f   // 2^17 fixed-point scale
#define FIXSI (1.0f / 131072.0f)
#define BIASI (1 << 22)  // low-field bias (|v_fix| < 2^22 since |v| < 32)

typedef unsigned int uint32;
typedef unsigned long long uint64;

static __device__ __forceinline__ uint32 f2bf(float f) {
    uint32 u = __float_as_uint(f);
    return (u + 0x7FFFu + ((u >> 16) & 1u)) >> 16;   // RNE to bf16
}
static __device__ __forceinline__ uint32 pack2(float lo, float hi) {
    return f2bf(lo) | (f2bf(hi) << 16);
}
static __device__ __forceinline__ float bf_lo(uint32 u) {
    return __uint_as_float(u << 16);
}
static __device__ __forceinline__ float bf_hi(uint32 u) {
    return __uint_as_float(u & 0xFFFF0000u);
}

// K1 (fused): blocks [0, GV) do the per-vertex dot-product table;
// blocks [GV, GV+NCHUNK) do the per-chunk dst histogram. The two jobs
// are independent; fusing overlaps count's 6.4MB read under precompute's
// 19.2MB read and drops one launch bubble.
__global__ __launch_bounds__(256)
void precount_kernel(const float* __restrict__ x,
                     const float* __restrict__ w_self0,
                     const float* __restrict__ w_n00,
                     const float* __restrict__ w_n10,
                     const float* __restrict__ w_self11,
                     const float* __restrict__ w_n01,
                     const float* __restrict__ w_n11,
                     uint32* __restrict__ table,   // 8 u32/vertex
                     float* __restrict__ selfbuf,
                     const int* __restrict__ dst,
                     int* __restrict__ cntmat,
                     int V, int E, int GV, int NB) {
    __shared__ float stage[256 * 49];   // 50KB (count role aliases as hist)
    int tid = threadIdx.x;

    if ((int)blockIdx.x >= GV) {
        // ---- count role: per-chunk histogram -> cntmat[bin][chunk] ----
        int* hist = (int*)stage;
        int b = blockIdx.x - GV;
        int lo = b * CHUNK;
        int hi = min(E, lo + CHUNK);
        for (int i = tid; i < NB; i += 256) hist[i] = 0;
        __syncthreads();
        for (int e = lo + tid; e < hi; e += 256)
            atomicAdd(&hist[dst[e] >> VB_SHIFT], 1);
        __syncthreads();
        for (int i = tid; i < NB; i += 256)
            cntmat[(size_t)i * NCHUNK + b] = hist[i];
        return;
    }

    // ---- precompute role: 256 rows staged in LDS, stride 49 floats ----
    int v0 = blockIdx.x * 256;
    int nv = min(256, V - v0);
    if (nv <= 0) return;
    {
        const float4* x4 = (const float4*)(x + (size_t)v0 * 48);
        int n4 = nv * 12;
        for (int j = tid; j < n4; j += 256) {
            float4 f = x4[j];
            float* dp = stage + (j / 12) * 49 + (j % 12) * 4;
            dp[0] = f.x; dp[1] = f.y; dp[2] = f.z; dp[3] = f.w;
        }
    }
    __syncthreads();
    if (tid >= nv) return;
    int v = v0 + tid;
    const float* xr = stage + tid * 49;
    float d00 = 0.f, aw0 = 0.f, bw0 = 0.f, aw1 = 0.f, bw1 = 0.f;
    float d01a = 0.f, d01b = 0.f;
    float aP = 0.f, bP = 0.f, aQ = 0.f, bQ = 0.f;
    float aR = 0.f, bR = 0.f, aS = 0.f, bS = 0.f;
    float selfmag = 0.f, t1s = 0.f, t2s = 0.f;
#pragma unroll
    for (int i = 0; i < 16; ++i) {
        float x0 = xr[i];
        float a  = xr[16 + 2 * i];
        float b  = xr[17 + 2 * i];
        d00     += x0 * w_n00[i];
        selfmag += x0 * w_self0[i];
        d01a    += x0 * w_n01[i * 2 + 0];
        d01b    += x0 * w_n01[i * 2 + 1];
        float w0 = w_n10[i * 2 + 0], w1 = w_n10[i * 2 + 1];
        aw0 += a * w0;  bw0 += b * w0;
        aw1 += a * w1;  bw1 += b * w1;
        float p = w_n11[i * 4 + 0], q = w_n11[i * 4 + 1];
        float r = w_n11[i * 4 + 2], s = w_n11[i * 4 + 3];
        aP += a * p;  bP += b * p;
        aQ += a * q;  bQ += b * q;
        aR += a * r;  bR += b * r;
        aS += a * s;  bS += b * s;
        float sa_ = w_self11[i * 2 + 0], sb_ = w_self11[i * 2 + 1];
        t1s += a * sa_ - b * sb_;
        t2s += b * sa_ + a * sb_;
    }
    uint4 w0, w1;
    w0.x = pack2(d00, aw0);  w0.y = pack2(bw0, aw1);
    w0.z = pack2(bw1, d01a); w0.w = pack2(d01b, aP);
    w1.x = pack2(bP, aQ);    w1.y = pack2(bQ, aR);
    w1.z = pack2(bR, aS);    w1.w = pack2(bS, 0.f);
    uint4* tp = (uint4*)(table + (size_t)v * 8);
    tp[0] = w0;  tp[1] = w1;
    float* sf = selfbuf + (size_t)v * 4;
    sf[0] = selfmag; sf[1] = t1s; sf[2] = t2s; sf[3] = 0.f;
}

// K3: one wave per bin. Padded (8-aligned) exclusive prefix over the 512
// chunk counts -> padprefT[chunk][bin] (stride MAXNB); padtotal[bin].
__global__ __launch_bounds__(256)
void padscan_kernel(const int* __restrict__ cntmat,
                    int* __restrict__ padprefT,
                    int* __restrict__ padtotal,
                    int NB) {
    int lane = threadIdx.x & 63;
    int wv = threadIdx.x >> 6;
    int bin = blockIdx.x * 4 + wv;
    if (bin >= NB) return;
    const int* row = cntmat + (size_t)bin * NCHUNK;
    int c[8], p[8];
#pragma unroll
    for (int j = 0; j < 8; ++j) {
        c[j] = row[lane * 8 + j];
        p[j] = (c[j] + 7) & ~7;
    }
    int e[8];
    int run = 0;
#pragma unroll
    for (int j = 0; j < 8; ++j) { e[j] = run; run += p[j]; }
    int T = run;
    int incl = T;
#pragma unroll
    for (int d = 1; d < 64; d <<= 1) {
        int n = __shfl_up(incl, d);
        if (lane >= d) incl += n;
    }
    int base = incl - T;
#pragma unroll
    for (int j = 0; j < 8; ++j)
        padprefT[(size_t)(lane * 8 + j) * MAXNB + bin] = base + e[j];
    if (lane == 63) padtotal[bin] = incl;
}

// K4: exclusive scan of padtotal -> binpadbase[0..NB].
__global__ __launch_bounds__(512)
void binbase_kernel(const int* __restrict__ padtotal,
                    int* __restrict__ binpadbase,
                    int NB) {
    __shared__ int wsum[8];
    int t = threadIdx.x;
    int lane = t & 63;
    int wv = t >> 6;
    int val = (t < NB) ? padtotal[t] : 0;
    int incl = val;
#pragma unroll
    for (int d = 1; d < 64; d <<= 1) {
        int n = __shfl_up(incl, d);
        if (lane >= d) incl += n;
    }
    if (lane == 63) wsum[wv] = incl;
    __syncthreads();
    if (t < 8) {
        int wval = wsum[t], winc = wval;
#pragma unroll
        for (int d = 1; d < 8; d <<= 1) {
            int n = __shfl_up(winc, d);
            if (lane >= d) winc += n;
        }
        wsum[t] = winc - wval;
    }
    __syncthreads();
    int ex = incl - val + wsum[wv];
    if (t < NB) binpadbase[t] = ex;
    if (t == NB - 1) binpadbase[NB] = ex + val;
}

// K5: local LDS tuple-sort + compute + write into bin-major line-aligned
// runs at binpadbase[bin] + padprefT[chunk][bin].
__global__ __launch_bounds__(BIGT)
void scatter_kernel(const int* __restrict__ src,
                    const int* __restrict__ dst,
                    const float* __restrict__ angles,
                    const float* __restrict__ transporters,
                    const uint32* __restrict__ table,
                    const int* __restrict__ padprefT,
                    const int* __restrict__ binpadbase,
                    uint2* __restrict__ payload,
                    int E, int NB) {
    __shared__ int cnt_l[MAXNB];
    __shared__ int exoff_l[MAXNB];
    __shared__ int slot_l[MAXNB];
    __shared__ int wsum[16];
    __shared__ uint32 tw_src[CHUNK];
    __shared__ uint32 tw_ang[CHUNK];
    __shared__ uint32 tw_tr[CHUNK];
    __shared__ unsigned short tw_bin[CHUNK];

    int b = blockIdx.x;
    int lo = b * CHUNK;
    int hi = min(E, lo + CHUNK);
    int nloc = hi - lo;
    int tid = threadIdx.x;
    int lane = tid & 63;
    int wv = tid >> 6;

    for (int i = tid; i < NB; i += BIGT) cnt_l[i] = 0;
    __syncthreads();

    // pass1: histogram (dst stays L1/L2-warm for pass1b)
    for (int e = lo + tid; e < hi; e += BIGT)
        atomicAdd(&cnt_l[dst[e] >> VB_SHIFT], 1);
    __syncthreads();

    // local exclusive scan over NB counts (shfl two-level)
    int c = (tid < NB) ? cnt_l[tid] : 0;
    int incl = c;
#pragma unroll
    for (int d = 1; d < 64; d <<= 1) {
        int n = __shfl_up(incl, d);
        if (lane >= d) incl += n;
    }
    if (lane == 63) wsum[wv] = incl;
    __syncthreads();
    if (tid < 16) {
        int wval = wsum[tid], winc = wval;
#pragma unroll
        for (int d = 1; d < 16; d <<= 1) {
            int n = __shfl_up(winc, d);
            if (lane >= d) winc += n;
        }
        wsum[tid] = winc - wval;
    }
    __syncthreads();
    if (tid < NB) {
        int ex = incl - c + wsum[wv];
        exoff_l[tid] = ex;
        cnt_l[tid] = ex;                         // cursor
        slot_l[tid] = binpadbase[tid] + padprefT[(size_t)b * MAXNB + tid];
    }
    __syncthreads();

    // pass1b: coalesced reads; tuple -> bin-sorted LDS slot
    for (int e = lo + tid; e < hi; e += BIGT) {
        int d = dst[e];
        int bin = d >> VB_SHIFT;
        uint32 dl = (uint32)(d & (VB - 1));
        int pos = atomicAdd(&cnt_l[bin], 1);
        tw_src[pos] = (uint32)src[e] | (dl << 17);
        tw_ang[pos] = __float_as_uint(angles[e]);
        tw_tr[pos]  = __float_as_uint(transporters[e]);
        tw_bin[pos] = (unsigned short)bin;
    }
    __syncthreads();

    // pass2: compute in bin order, write line-aligned bin-major runs
    for (int k = tid; k < nloc; k += BIGT) {
        int bin = (int)tw_bin[k];
        uint32 w0i = tw_src[k];
        int s  = (int)(w0i & 0x1FFFFu);
        int dl = (int)(w0i >> 17);
        float ang = __uint_as_float(tw_ang[k]);
        float trv = __uint_as_float(tw_tr[k]);
        // native trig: args in [0, 2pi), err ~1e-6 << bf16 payload err
        float st = __sinf(ang), ct = __cosf(ang);
        float sg = __sinf(trv), cg = __cosf(trv);
        float c2t = ct * ct - st * st;
        float s2t = 2.0f * st * ct;

        const uint4* tp = (const uint4*)(table + (size_t)s * 8);
        uint4 W0 = tp[0], W1 = tp[1];
        float d00 = bf_lo(W0.x), aw0 = bf_hi(W0.x);
        float bw0 = bf_lo(W0.y), aw1 = bf_hi(W0.y);
        float bw1 = bf_lo(W0.z), d01a = bf_hi(W0.z);
        float d01b = bf_lo(W0.w), aP = bf_hi(W0.w);
        float bP = bf_lo(W1.x), aQ = bf_hi(W1.x);
        float bQ = bf_lo(W1.y), aR = bf_hi(W1.y);
        float bR = bf_lo(W1.z), aS = bf_hi(W1.z);
        float bS = bf_lo(W1.w);

        float u1w0 = cg * aw0 - sg * bw0, u2w0 = sg * aw0 + cg * bw0;
        float u1w1 = cg * aw1 - sg * bw1, u2w1 = sg * aw1 + cg * bw1;
        float m0 = d00 + ct * u1w0 + st * u2w0 - st * u1w1 + ct * u2w1;

        float u1p = cg * aP - sg * bP, u2p = sg * aP + cg * bP;
        float u1q = cg * aQ - sg * bQ, u2q = sg * aQ + cg * bQ;
        float u1r = cg * aR - sg * bR, u2r = sg * aR + cg * bR;
        float u1s = cg * aS - sg * bS, u2s = sg * aS + cg * bS;

        float mv1 = d01a * ct - d01b * st
                  + u1p - u2q
                  + c2t * u1r + s2t * u2r
                  - (s2t * u1s - c2t * u2s);
        float mv2 = d01a * st + d01b * ct
                  + u2p + u1q
                  + s2t * u1r - c2t * u2r
                  + c2t * u1s + s2t * u2s;

        uint2 pl;
        pl.x = pack2(m0, mv1);
        pl.y = f2bf(mv2) | ((uint32)dl << 16);
        payload[slot_l[bin] + (k - exoff_l[bin])] = pl;
    }
}

// K6: one block per bin. Contiguous stream read of the bin's padded region;
// run starts read straight from padprefT (no scan); TWO packed u64
// fixed-point LDS atomics per edge (ds_add_u64). Low field biased +2^22
// per add so it stays non-negative (no carry into high field); per-copy
// add count rides in word2's high half and removes the bias at finalize.
__global__ __launch_bounds__(BIGT)
void bucket_kernel(const uint2* __restrict__ payload,
                   const int* __restrict__ cntmat,
                   const int* __restrict__ padprefT,
                   const int* __restrict__ binpadbase,
                   const float* __restrict__ selfbuf,
                   const float* __restrict__ e1,
                   const float* __restrict__ e2,
                   float* __restrict__ out,
                   int V, int NB) {
    __shared__ uint64 acc[8][VB * 2];    // 32KB, wave-pair w=tid>>7 owns copy
    __shared__ int len_l[NCHUNK];
    __shared__ int pstart_l[NCHUNK];
    __shared__ unsigned short group2run[2048];
    int bin = blockIdx.x;
    int tid = threadIdx.x;
    for (int i = tid; i < 8 * VB * 2; i += BIGT) ((uint64*)acc)[i] = 0ULL;

    if (tid < NCHUNK) {
        int len = cntmat[(size_t)bin * NCHUNK + tid];
        int ps  = padprefT[(size_t)tid * MAXNB + bin];
        len_l[tid] = len;
        pstart_l[tid] = ps;
        int g0 = ps >> 3, gn = (len + 7) >> 3;
        for (int j = 0; j < gn; ++j)
            group2run[g0 + j] = (unsigned short)tid;
    }
    __syncthreads();

    int base = binpadbase[bin];
    int ptot = binpadbase[bin + 1] - base;
    uint64* myacc = acc[tid >> 7];
    for (int k = tid; k < ptot; k += BIGT) {
        int r = (int)group2run[k >> 3];
        int local = k - pstart_l[r];
        if (local < len_l[r]) {
            uint2 pl = payload[base + k];
            float m0  = bf_lo(pl.x);
            float mv1 = bf_hi(pl.x);
            float mv2 = bf_lo(pl.y);
            int dl = (int)(pl.y >> 16);
            int m0f  = __float2int_rn(m0  * FIXS);
            int mv1f = __float2int_rn(mv1 * FIXS);
            int mv2f = __float2int_rn(mv2 * FIXS);
            uint64 pa = (uint64)(uint32)(m0f + BIASI)
                      | ((uint64)(uint32)mv1f << 32);
            uint64 pb = (uint64)(uint32)(mv2f + BIASI)
                      | (1ULL << 32);
            atomicAdd(&myacc[dl * 2 + 0], pa);
            atomicAdd(&myacc[dl * 2 + 1], pb);
        }
    }
    __syncthreads();
    if (tid < VB) {
        int v = bin * VB + tid;
        if (v < V) {
            int cnt = 0, m0s = 0, mv1s = 0, mv2s = 0;
#pragma unroll
            for (int w = 0; w < 8; ++w) {
                uint64 a = acc[w][tid * 2 + 0];
                uint64 b = acc[w][tid * 2 + 1];
                uint32 nw = (uint32)(b >> 32);
                cnt  += (int)nw;
                m0s  += (int)((uint32)a - nw * (uint32)BIASI);
                mv1s += (int)(a >> 32);
                mv2s += (int)((uint32)b - nw * (uint32)BIASI);
            }
            float A0 = (float)m0s  * FIXSI;
            float A1 = (float)mv1s * FIXSI;
            float A2 = (float)mv2s * FIXSI;
            float inv = 1.0f / fmaxf((float)cnt, 1.0f);
            const float* sf = selfbuf + (size_t)v * 4;
            float mag = A0 * inv + sf[0];
            float t1  = A1 * inv + sf[1];
            float t2  = A2 * inv + sf[2];
            float scale = 2.0f / (1.0f + expf(-mag));
            float e1x = e1[v * 3 + 0], e1y = e1[v * 3 + 1], e1z = e1[v * 3 + 2];
            float e2x = e2[v * 3 + 0], e2y = e2[v * 3 + 1], e2z = e2[v * 3 + 2];
            out[v * 3 + 0] = (t1 * e1x + t2 * e2x) * scale;
            out[v * 3 + 1] = (t1 * e1y + t2 * e2y) * scale;
            out[v * 3 + 2] = (t1 * e1z + t2 * e2z) * scale;
        }
    }
}

extern "C" void kernel_launch(void* const* d_in, const int* in_sizes, int n_in,
                              void* d_out, int out_size, void* d_ws, size_t ws_size,
                              hipStream_t stream) {
    const float* x            = (const float*)d_in[0];
    const int*   edge_index   = (const int*)d_in[1];
    const float* angles       = (const float*)d_in[2];
    const float* transporters = (const float*)d_in[3];
    const float* e1           = (const float*)d_in[4];
    const float* e2           = (const float*)d_in[5];
    const float* w_self0      = (const float*)d_in[6];
    const float* w_n00        = (const float*)d_in[7];
    const float* w_n10        = (const float*)d_in[8];
    const float* w_self11     = (const float*)d_in[9];
    const float* w_n01        = (const float*)d_in[10];
    const float* w_n11        = (const float*)d_in[11];
    float* out = (float*)d_out;

    int V = in_sizes[0] / 48;
    int E = in_sizes[2];
    const int* src = edge_index;
    const int* dst = edge_index + E;

    int NB = (V + VB - 1) / VB;              // 391
    int nchunk = (E + CHUNK - 1) / CHUNK;    // 512

    char* p = (char*)d_ws;
    int* cntmat     = (int*)p;  p += (size_t)MAXNB * NCHUNK * 4;  // 0.8MB
    int* padprefT   = (int*)p;  p += (size_t)NCHUNK * MAXNB * 4;  // 0.8MB
    int* padtotal   = (int*)p;  p += (size_t)MAXNB * 4;
    int* binpadbase = (int*)p;  p += (size_t)(MAXNB + 1) * 4;
    uint32* table  = (uint32*)p;  p += (size_t)V * 8 * 4;         // 3.2MB
    float* selfbuf = (float*)p;   p += (size_t)V * 4 * 4;         // 1.6MB
    p = (char*)(((uintptr_t)p + 63) & ~(uintptr_t)63);
    uint2* payload = (uint2*)p;   // <= (E + 8*NCHUNK*NB)*8B ~ 25.6MB

    int gv = (V + 255) / 256;                // 391

    precount_kernel<<<gv + nchunk, 256, 0, stream>>>(
        x, w_self0, w_n00, w_n10, w_self11, w_n01, w_n11,
        table, selfbuf, dst, cntmat, V, E, gv, NB);
    padscan_kernel<<<(NB + 3) / 4, 256, 0, stream>>>(cntmat, padprefT,
                                                     padtotal, NB);
    binbase_kernel<<<1, 512, 0, stream>>>(padtotal, binpadbase, NB);
    scatter_kernel<<<nchunk, BIGT, 0, stream>>>(src, dst, angles,
                                                transporters, table,
                                                padprefT, binpadbase,
                                                payload, E, NB);
    bucket_kernel<<<NB, BIGT, 0, stream>>>(payload, cntmat, padprefT,
                                           binpadbase, selfbuf,
                                           e1, e2, out, V, NB);
}

// Round 2
// 138.335 us; speedup vs baseline: 1.0414x; 1.0414x over previous
//
#include <hip/hip_runtime.h>
#include <math.h>

// EquivariantWSSHead: V=100000 vertices, E=1600000 edges, C0=C1=16.
//
// R1..R12: zero-global-atomic bucket binning; bf16 table (3.2MB) + 8B
//   payload; LDS tuple-sort so scatter reads AND writes are sequential.
// R13 (fused): per-kernel time is real; dur_us has ~70us harness floor
//   (256MB workspace poison-fill = 42us/iter, visible as top dispatches).
// R14: bin-major line-aligned payload; bucket invariant was 6.4M FLOAT
//   LDS atomics (CAS-loop lowering).
// R15: fixed-point INT accumulate (scale 2^17) -> native ds_add_u32.
// R16: packed u64 LDS atomics (2/edge), precompute+count fused, __sinf.
//   NEUTRAL (144.1 vs 141.9) => bucket atomics NOT the bottleneck;
//   remaining ~74us of kernel time is distributed overhead.
// R17 (this round): remove redundant work + launch serialization:
//   a) scatter no longer rebuilds the chunk histogram (drops a full dst
//      read + 1.6M LDS atomics): count role writes cntmatT[chunk][bin]
//      (coalesced) and scatter reads its row directly.
//   b) binbase_kernel deleted: scatter fuses the padtotal scan into its
//      existing shfl-scan (two scans, one barrier pair); bucket gets its
//      base via a butterfly reduce of padtotal[0..bin).
//   c) pad-to-4 (32B lines) instead of pad-to-8: bucket loop iterations
//      and payload footprint -17% (avg count/(chunk,bin) is only ~8).

#define VB 256           // vertices per bucket
#define VB_SHIFT 8
#define MAXNB 400        // NB = ceil(V/256) = 391 for V=100000
#define CHUNK 3125       // edges per chunk
#define NCHUNK 512       // chunks (E/CHUNK)
#define BIGT 1024
#define FIXS 131072.0f   // 2^17 fixed-point scale
#define FIXSI (1.0f / 131072.0f)
#define BIASI (1 << 22)  // low-field bias (|v_fix| < 2^22 since |v| < 32)

typedef unsigned int uint32;
typedef unsigned long long uint64;

static __device__ __forceinline__ uint32 f2bf(float f) {
    uint32 u = __float_as_uint(f);
    return (u + 0x7FFFu + ((u >> 16) & 1u)) >> 16;   // RNE to bf16
}
static __device__ __forceinline__ uint32 pack2(float lo, float hi) {
    return f2bf(lo) | (f2bf(hi) << 16);
}
static __device__ __forceinline__ float bf_lo(uint32 u) {
    return __uint_as_float(u << 16);
}
static __device__ __forceinline__ float bf_hi(uint32 u) {
    return __uint_as_float(u & 0xFFFF0000u);
}

// K1 (fused): blocks [0, GV) do the per-vertex dot-product table;
// blocks [GV, GV+NCHUNK) do the per-chunk dst histogram.
__global__ __launch_bounds__(256)
void precount_kernel(const float* __restrict__ x,
                     const float* __restrict__ w_self0,
                     const float* __restrict__ w_n00,
                     const float* __restrict__ w_n10,
                     const float* __restrict__ w_self11,
                     const float* __restrict__ w_n01,
                     const float* __restrict__ w_n11,
                     uint32* __restrict__ table,   // 8 u32/vertex
                     float* __restrict__ selfbuf,
                     const int* __restrict__ dst,
                     int* __restrict__ cntmat,     // [bin][chunk]
                     int* __restrict__ cntmatT,    // [chunk][bin]
                     int V, int E, int GV, int NB) {
    __shared__ float stage[256 * 49];   // 50KB (count role aliases as hist)
    int tid = threadIdx.x;

    if ((int)blockIdx.x >= GV) {
        // ---- count role ----
        int* hist = (int*)stage;
        int b = blockIdx.x - GV;
        int lo = b * CHUNK;
        int hi = min(E, lo + CHUNK);
        for (int i = tid; i < NB; i += 256) hist[i] = 0;
        __syncthreads();
        for (int e = lo + tid; e < hi; e += 256)
            atomicAdd(&hist[dst[e] >> VB_SHIFT], 1);
        __syncthreads();
        for (int i = tid; i < NB; i += 256) {
            int h = hist[i];
            cntmat[(size_t)i * NCHUNK + b] = h;      // row per bin (padscan)
            cntmatT[(size_t)b * MAXNB + i] = h;      // row per chunk (scatter)
        }
        return;
    }

    // ---- precompute role ----
    int v0 = blockIdx.x * 256;
    int nv = min(256, V - v0);
    if (nv <= 0) return;
    {
        const float4* x4 = (const float4*)(x + (size_t)v0 * 48);
        int n4 = nv * 12;
        for (int j = tid; j < n4; j += 256) {
            float4 f = x4[j];
            float* dp = stage + (j / 12) * 49 + (j % 12) * 4;
            dp[0] = f.x; dp[1] = f.y; dp[2] = f.z; dp[3] = f.w;
        }
    }
    __syncthreads();
    if (tid >= nv) return;
    int v = v0 + tid;
    const float* xr = stage + tid * 49;
    float d00 = 0.f, aw0 = 0.f, bw0 = 0.f, aw1 = 0.f, bw1 = 0.f;
    float d01a = 0.f, d01b = 0.f;
    float aP = 0.f, bP = 0.f, aQ = 0.f, bQ = 0.f;
    float aR = 0.f, bR = 0.f, aS = 0.f, bS = 0.f;
    float selfmag = 0.f, t1s = 0.f, t2s = 0.f;
#pragma unroll
    for (int i = 0; i < 16; ++i) {
        float x0 = xr[i];
        float a  = xr[16 + 2 * i];
        float b  = xr[17 + 2 * i];
        d00     += x0 * w_n00[i];
        selfmag += x0 * w_self0[i];
        d01a    += x0 * w_n01[i * 2 + 0];
        d01b    += x0 * w_n01[i * 2 + 1];
        float w0 = w_n10[i * 2 + 0], w1 = w_n10[i * 2 + 1];
        aw0 += a * w0;  bw0 += b * w0;
        aw1 += a * w1;  bw1 += b * w1;
        float p = w_n11[i * 4 + 0], q = w_n11[i * 4 + 1];
        float r = w_n11[i * 4 + 2], s = w_n11[i * 4 + 3];
        aP += a * p;  bP += b * p;
        aQ += a * q;  bQ += b * q;
        aR += a * r;  bR += b * r;
        aS += a * s;  bS += b * s;
        float sa_ = w_self11[i * 2 + 0], sb_ = w_self11[i * 2 + 1];
        t1s += a * sa_ - b * sb_;
        t2s += b * sa_ + a * sb_;
    }
    uint4 w0, w1;
    w0.x = pack2(d00, aw0);  w0.y = pack2(bw0, aw1);
    w0.z = pack2(bw1, d01a); w0.w = pack2(d01b, aP);
    w1.x = pack2(bP, aQ);    w1.y = pack2(bQ, aR);
    w1.z = pack2(bR, aS);    w1.w = pack2(bS, 0.f);
    uint4* tp = (uint4*)(table + (size_t)v * 8);
    tp[0] = w0;  tp[1] = w1;
    float* sf = selfbuf + (size_t)v * 4;
    sf[0] = selfmag; sf[1] = t1s; sf[2] = t2s; sf[3] = 0.f;
}

// K2: one wave per bin. Padded (4-aligned) exclusive prefix over the 512
// chunk counts -> padprefT[chunk][bin] (stride MAXNB); padtotal[bin].
__global__ __launch_bounds__(256)
void padscan_kernel(const int* __restrict__ cntmat,
                    int* __restrict__ padprefT,
                    int* __restrict__ padtotal,
                    int NB) {
    int lane = threadIdx.x & 63;
    int wv = threadIdx.x >> 6;
    int bin = blockIdx.x * 4 + wv;
    if (bin >= NB) return;
    const int* row = cntmat + (size_t)bin * NCHUNK;
    int c[8], p[8];
#pragma unroll
    for (int j = 0; j < 8; ++j) {
        c[j] = row[lane * 8 + j];
        p[j] = (c[j] + 3) & ~3;                      // pad to 4 (32B lines)
    }
    int e[8];
    int run = 0;
#pragma unroll
    for (int j = 0; j < 8; ++j) { e[j] = run; run += p[j]; }
    int T = run;
    int incl = T;
#pragma unroll
    for (int d = 1; d < 64; d <<= 1) {
        int n = __shfl_up(incl, d);
        if (lane >= d) incl += n;
    }
    int base = incl - T;
#pragma unroll
    for (int j = 0; j < 8; ++j)
        padprefT[(size_t)(lane * 8 + j) * MAXNB + bin] = base + e[j];
    if (lane == 63) padtotal[bin] = incl;
}

// K3: local LDS tuple-sort + compute + write into bin-major line-aligned
// runs. Chunk bin-counts come from cntmatT (no histogram rebuild); the
// cross-bin base comes from an in-block scan of padtotal (no binbase
// kernel). Two shfl-scans share one barrier pair.
__global__ __launch_bounds__(BIGT)
void scatter_kernel(const int* __restrict__ src,
                    const int* __restrict__ dst,
                    const float* __restrict__ angles,
                    const float* __restrict__ transporters,
                    const uint32* __restrict__ table,
                    const int* __restrict__ cntmatT,
                    const int* __restrict__ padprefT,
                    const int* __restrict__ padtotal,
                    uint2* __restrict__ payload,
                    int E, int NB) {
    __shared__ int cnt_l[MAXNB];
    __shared__ int exoff_l[MAXNB];
    __shared__ int slot_l[MAXNB];
    __shared__ int wsumA[16];
    __shared__ int wsumB[16];
    __shared__ uint32 tw_src[CHUNK];
    __shared__ uint32 tw_ang[CHUNK];
    __shared__ uint32 tw_tr[CHUNK];
    __shared__ unsigned short tw_bin[CHUNK];

    int b = blockIdx.x;
    int lo = b * CHUNK;
    int hi = min(E, lo + CHUNK);
    int nloc = hi - lo;
    int tid = threadIdx.x;
    int lane = tid & 63;
    int wv = tid >> 6;

    // two exclusive scans over tid<NB: A = this chunk's bin counts
    // (-> exoff/cursor), B = padtotal (-> cross-bin padded base).
    int ccv = 0, ptv = 0;
    if (tid < NB) {
        ccv = cntmatT[(size_t)b * MAXNB + tid];
        ptv = padtotal[tid];
    }
    int inclA = ccv, inclB = ptv;
#pragma unroll
    for (int d = 1; d < 64; d <<= 1) {
        int nA = __shfl_up(inclA, d);
        int nB = __shfl_up(inclB, d);
        if (lane >= d) { inclA += nA; inclB += nB; }
    }
    if (lane == 63) { wsumA[wv] = inclA; wsumB[wv] = inclB; }
    __syncthreads();
    if (tid < 16) {
        int wa = wsumA[tid], wb = wsumB[tid];
        int ia = wa, ib = wb;
#pragma unroll
        for (int d = 1; d < 16; d <<= 1) {
            int nA = __shfl_up(ia, d);
            int nB = __shfl_up(ib, d);
            if (lane >= d) { ia += nA; ib += nB; }
        }
        wsumA[tid] = ia - wa;
        wsumB[tid] = ib - wb;
    }
    __syncthreads();
    if (tid < NB) {
        int exA = inclA - ccv + wsumA[wv];
        int exB = inclB - ptv + wsumB[wv];
        exoff_l[tid] = exA;
        cnt_l[tid] = exA;                            // cursor
        slot_l[tid] = exB + padprefT[(size_t)b * MAXNB + tid];
    }
    __syncthreads();

    // pass1b: coalesced reads; tuple -> bin-sorted LDS slot
    for (int e = lo + tid; e < hi; e += BIGT) {
        int d = dst[e];
        int bin = d >> VB_SHIFT;
        uint32 dl = (uint32)(d & (VB - 1));
        int pos = atomicAdd(&cnt_l[bin], 1);
        tw_src[pos] = (uint32)src[e] | (dl << 17);
        tw_ang[pos] = __float_as_uint(angles[e]);
        tw_tr[pos]  = __float_as_uint(transporters[e]);
        tw_bin[pos] = (unsigned short)bin;
    }
    __syncthreads();

    // pass2: compute in bin order, write line-aligned bin-major runs
    for (int k = tid; k < nloc; k += BIGT) {
        int bin = (int)tw_bin[k];
        uint32 w0i = tw_src[k];
        int s  = (int)(w0i & 0x1FFFFu);
        int dl = (int)(w0i >> 17);
        float ang = __uint_as_float(tw_ang[k]);
        float trv = __uint_as_float(tw_tr[k]);
        // native trig: args in [0, 2pi), err ~1e-6 << bf16 payload err
        float st = __sinf(ang), ct = __cosf(ang);
        float sg = __sinf(trv), cg = __cosf(trv);
        float c2t = ct * ct - st * st;
        float s2t = 2.0f * st * ct;

        const uint4* tp = (const uint4*)(table + (size_t)s * 8);
        uint4 W0 = tp[0], W1 = tp[1];
        float d00 = bf_lo(W0.x), aw0 = bf_hi(W0.x);
        float bw0 = bf_lo(W0.y), aw1 = bf_hi(W0.y);
        float bw1 = bf_lo(W0.z), d01a = bf_hi(W0.z);
        float d01b = bf_lo(W0.w), aP = bf_hi(W0.w);
        float bP = bf_lo(W1.x), aQ = bf_hi(W1.x);
        float bQ = bf_lo(W1.y), aR = bf_hi(W1.y);
        float bR = bf_lo(W1.z), aS = bf_hi(W1.z);
        float bS = bf_lo(W1.w);

        float u1w0 = cg * aw0 - sg * bw0, u2w0 = sg * aw0 + cg * bw0;
        float u1w1 = cg * aw1 - sg * bw1, u2w1 = sg * aw1 + cg * bw1;
        float m0 = d00 + ct * u1w0 + st * u2w0 - st * u1w1 + ct * u2w1;

        float u1p = cg * aP - sg * bP, u2p = sg * aP + cg * bP;
        float u1q = cg * aQ - sg * bQ, u2q = sg * aQ + cg * bQ;
        float u1r = cg * aR - sg * bR, u2r = sg * aR + cg * bR;
        float u1s = cg * aS - sg * bS, u2s = sg * aS + cg * bS;

        float mv1 = d01a * ct - d01b * st
                  + u1p - u2q
                  + c2t * u1r + s2t * u2r
                  - (s2t * u1s - c2t * u2s);
        float mv2 = d01a * st + d01b * ct
                  + u2p + u1q
                  + s2t * u1r - c2t * u2r
                  + c2t * u1s + s2t * u2s;

        uint2 pl;
        pl.x = pack2(m0, mv1);
        pl.y = f2bf(mv2) | ((uint32)dl << 16);
        payload[slot_l[bin] + (k - exoff_l[bin])] = pl;
    }
}

// K4: one block per bin. Contiguous stream read of the bin's padded region;
// run starts read straight from padprefT; cross-bin base via butterfly
// reduce of padtotal[0..bin); TWO packed u64 fixed-point LDS atomics per
// edge (ds_add_u64); fused finalize.
__global__ __launch_bounds__(BIGT)
void bucket_kernel(const uint2* __restrict__ payload,
                   const int* __restrict__ cntmat,
                   const int* __restrict__ padprefT,
                   const int* __restrict__ padtotal,
                   const float* __restrict__ selfbuf,
                   const float* __restrict__ e1,
                   const float* __restrict__ e2,
                   float* __restrict__ out,
                   int V, int NB) {
    __shared__ uint64 acc[8][VB * 2];    // 32KB, wave-pair w=tid>>7 owns copy
    __shared__ int len_l[NCHUNK];
    __shared__ int pstart_l[NCHUNK];
    __shared__ unsigned short group2run[2048];   // ptot/4 <= ~1300 used
    __shared__ int redw[16];
    int bin = blockIdx.x;
    int tid = threadIdx.x;
    int lane = tid & 63;
    int wv = tid >> 6;
    for (int i = tid; i < 8 * VB * 2; i += BIGT) ((uint64*)acc)[i] = 0ULL;

    // base = sum(padtotal[0..bin)) via butterfly reduce (bin < NB <= 1024)
    int rv = (tid < bin) ? padtotal[tid] : 0;
#pragma unroll
    for (int d = 1; d < 64; d <<= 1) rv += __shfl_xor(rv, d);
    if (lane == 0) redw[wv] = rv;

    if (tid < NCHUNK) {
        int len = cntmat[(size_t)bin * NCHUNK + tid];
        int ps  = padprefT[(size_t)tid * MAXNB + bin];
        len_l[tid] = len;
        pstart_l[tid] = ps;
        int g0 = ps >> 2, gn = (len + 3) >> 2;
        for (int j = 0; j < gn; ++j)
            group2run[g0 + j] = (unsigned short)tid;
    }
    __syncthreads();

    int base = 0;
#pragma unroll
    for (int w = 0; w < 16; ++w) base += redw[w];
    int ptot = padtotal[bin];

    uint64* myacc = acc[tid >> 7];
    for (int k = tid; k < ptot; k += BIGT) {
        int r = (int)group2run[k >> 2];
        int local = k - pstart_l[r];
        if (local < len_l[r]) {
            uint2 pl = payload[base + k];
            float m0  = bf_lo(pl.x);
            float mv1 = bf_hi(pl.x);
            float mv2 = bf_lo(pl.y);
            int dl = (int)(pl.y >> 16);
            int m0f  = __float2int_rn(m0  * FIXS);
            int mv1f = __float2int_rn(mv1 * FIXS);
            int mv2f = __float2int_rn(mv2 * FIXS);
            uint64 pa = (uint64)(uint32)(m0f + BIASI)
                      | ((uint64)(uint32)mv1f << 32);
            uint64 pb = (uint64)(uint32)(mv2f + BIASI)
                      | (1ULL << 32);
            atomicAdd(&myacc[dl * 2 + 0], pa);
            atomicAdd(&myacc[dl * 2 + 1], pb);
        }
    }
    __syncthreads();
    if (tid < VB) {
        int v = bin * VB + tid;
        if (v < V) {
            int cnt = 0, m0s = 0, mv1s = 0, mv2s = 0;
#pragma unroll
            for (int w = 0; w < 8; ++w) {
                uint64 a = acc[w][tid * 2 + 0];
                uint64 b = acc[w][tid * 2 + 1];
                uint32 nw = (uint32)(b >> 32);
                cnt  += (int)nw;
                m0s  += (int)((uint32)a - nw * (uint32)BIASI);
                mv1s += (int)(a >> 32);
                mv2s += (int)((uint32)b - nw * (uint32)BIASI);
            }
            float A0 = (float)m0s  * FIXSI;
            float A1 = (float)mv1s * FIXSI;
            float A2 = (float)mv2s * FIXSI;
            float inv = 1.0f / fmaxf((float)cnt, 1.0f);
            const float* sf = selfbuf + (size_t)v * 4;
            float mag = A0 * inv + sf[0];
            float t1  = A1 * inv + sf[1];
            float t2  = A2 * inv + sf[2];
            float scale = 2.0f / (1.0f + expf(-mag));
            float e1x = e1[v * 3 + 0], e1y = e1[v * 3 + 1], e1z = e1[v * 3 + 2];
            float e2x = e2[v * 3 + 0], e2y = e2[v * 3 + 1], e2z = e2[v * 3 + 2];
            out[v * 3 + 0] = (t1 * e1x + t2 * e2x) * scale;
            out[v * 3 + 1] = (t1 * e1y + t2 * e2y) * scale;
            out[v * 3 + 2] = (t1 * e1z + t2 * e2z) * scale;
        }
    }
}

extern "C" void kernel_launch(void* const* d_in, const int* in_sizes, int n_in,
                              void* d_out, int out_size, void* d_ws, size_t ws_size,
                              hipStream_t stream) {
    const float* x            = (const float*)d_in[0];
    const int*   edge_index   = (const int*)d_in[1];
    const float* angles       = (const float*)d_in[2];
    const float* transporters = (const float*)d_in[3];
    const float* e1           = (const float*)d_in[4];
    const float* e2           = (const float*)d_in[5];
    const float* w_self0      = (const float*)d_in[6];
    const float* w_n00        = (const float*)d_in[7];
    const float* w_n10        = (const float*)d_in[8];
    const float* w_self11     = (const float*)d_in[9];
    const float* w_n01        = (const float*)d_in[10];
    const float* w_n11        = (const float*)d_in[11];
    float* out = (float*)d_out;

    int V = in_sizes[0] / 48;
    int E = in_sizes[2];
    const int* src = edge_index;
    const int* dst = edge_index + E;

    int NB = (V + VB - 1) / VB;              // 391
    int nchunk = (E + CHUNK - 1) / CHUNK;    // 512

    char* p = (char*)d_ws;
    int* cntmat     = (int*)p;  p += (size_t)MAXNB * NCHUNK * 4;  // 0.8MB
    int* cntmatT    = (int*)p;  p += (size_t)NCHUNK * MAXNB * 4;  // 0.8MB
    int* padprefT   = (int*)p;  p += (size_t)NCHUNK * MAXNB * 4;  // 0.8MB
    int* padtotal   = (int*)p;  p += (size_t)MAXNB * 4;
    uint32* table  = (uint32*)p;  p += (size_t)V * 8 * 4;         // 3.2MB
    float* selfbuf = (float*)p;   p += (size_t)V * 4 * 4;         // 1.6MB
    p = (char*)(((uintptr_t)p + 63) & ~(uintptr_t)63);
    uint2* payload = (uint2*)p;   // <= (E + 3*NCHUNK*NB)*8B ~ 17.6MB

    int gv = (V + 255) / 256;                // 391

    precount_kernel<<<gv + nchunk, 256, 0, stream>>>(
        x, w_self0, w_n00, w_n10, w_self11, w_n01, w_n11,
        table, selfbuf, dst, cntmat, cntmatT, V, E, gv, NB);
    padscan_kernel<<<(NB + 3) / 4, 256, 0, stream>>>(cntmat, padprefT,
                                                     padtotal, NB);
    scatter_kernel<<<nchunk, BIGT, 0, stream>>>(src, dst, angles,
                                                transporters, table,
                                                cntmatT, padprefT, padtotal,
                                                payload, E, NB);
    bucket_kernel<<<NB, BIGT, 0, stream>>>(payload, cntmat, padprefT,
                                           padtotal, selfbuf,
                                           e1, e2, out, V, NB);
}

// Round 3
// 138.294 us; speedup vs baseline: 1.0418x; 1.0003x over previous
//
#include <hip/hip_runtime.h>
#include <math.h>

// EquivariantWSSHead: V=100000 vertices, E=1600000 edges, C0=C1=16.
//
// R1..R12: zero-global-atomic bucket binning; bf16 table (3.2MB) + 8B
//   payload; LDS tuple-sort so scatter reads AND writes are sequential.
// R13 (fused): per-kernel time is real; dur_us has ~70us harness floor
//   (256MB workspace poison-fill = 42us/iter, visible as top dispatches).
// R14: bin-major line-aligned payload; bucket invariant was 6.4M FLOAT
//   LDS atomics (CAS-loop lowering).
// R15: fixed-point INT accumulate (scale 2^17) -> native ds_add_u32.
// R16: packed u64 LDS atomics (2/edge), precompute+count fused, __sinf.
//   NEUTRAL => bucket atomics not the bottleneck.
// R17: dropped scatter's histogram rebuild, deleted binbase kernel,
//   pad-to-4. -5.7us (138.3) => distributed structural overhead is real.
// R18 (this round): replace the exact-slot machinery with per-bin GLOBAL
//   CURSOR reservation (atomicAdd per (chunk,bin) ~200K ops, L2-pipelined,
//   latency hidden under the LDS sort). Deletes: count role (6.4MB dst
//   read + 1.6M LDS atomics), padscan kernel (+1 launch), scatter's
//   second scan + cntmatT/padprefT reads, bucket's group2run build +
//   per-iteration validity branch + butterfly base (now payload+(bin<<13),
//   n=fill[bin], dense E iterations instead of padded 1.9M).
//   Bin regions are fixed CAP=8192 slots (mean 4096, sigma 64 -> 64-sigma
//   margin); overflow clamped by skip-write so it cannot corrupt.

#define VB 256           // vertices per bucket
#define VB_SHIFT 8
#define MAXNB 400        // NB = ceil(V/256) = 391 for V=100000
#define CHUNK 3125       // edges per chunk
#define NCHUNK 512       // chunks (E/CHUNK)
#define BIGT 1024
#define CAP_SHIFT 13
#define CAP (1 << CAP_SHIFT)   // 8192 payload slots per bin
#define FIXS 131072.0f   // 2^17 fixed-point scale
#define FIXSI (1.0f / 131072.0f)
#define BIASI (1 << 22)  // low-field bias (|v_fix| < 2^22 since |v| < 32)

typedef unsigned int uint32;
typedef unsigned long long uint64;

static __device__ __forceinline__ uint32 f2bf(float f) {
    uint32 u = __float_as_uint(f);
    return (u + 0x7FFFu + ((u >> 16) & 1u)) >> 16;   // RNE to bf16
}
static __device__ __forceinline__ uint32 pack2(float lo, float hi) {
    return f2bf(lo) | (f2bf(hi) << 16);
}
static __device__ __forceinline__ float bf_lo(uint32 u) {
    return __uint_as_float(u << 16);
}
static __device__ __forceinline__ float bf_hi(uint32 u) {
    return __uint_as_float(u & 0xFFFF0000u);
}

// K1: per-vertex dot-product table (256 rows staged in LDS, stride 49
// floats, conflict-free). Block 0 additionally zeroes the bin cursors.
__global__ __launch_bounds__(256)
void precompute_kernel(const float* __restrict__ x,
                       const float* __restrict__ w_self0,
                       const float* __restrict__ w_n00,
                       const float* __restrict__ w_n10,
                       const float* __restrict__ w_self11,
                       const float* __restrict__ w_n01,
                       const float* __restrict__ w_n11,
                       uint32* __restrict__ table,   // 8 u32/vertex
                       float* __restrict__ selfbuf,
                       int* __restrict__ fill,       // bin cursors
                       int V, int NB) {
    __shared__ float stage[256 * 49];   // 50KB
    int tid = threadIdx.x;
    if (blockIdx.x == 0) {
        for (int i = tid; i < NB; i += 256) fill[i] = 0;
    }
    int v0 = blockIdx.x * 256;
    int nv = min(256, V - v0);
    if (nv <= 0) return;
    {
        const float4* x4 = (const float4*)(x + (size_t)v0 * 48);
        int n4 = nv * 12;
        for (int j = tid; j < n4; j += 256) {
            float4 f = x4[j];
            float* dp = stage + (j / 12) * 49 + (j % 12) * 4;
            dp[0] = f.x; dp[1] = f.y; dp[2] = f.z; dp[3] = f.w;
        }
    }
    __syncthreads();
    if (tid >= nv) return;
    int v = v0 + tid;
    const float* xr = stage + tid * 49;
    float d00 = 0.f, aw0 = 0.f, bw0 = 0.f, aw1 = 0.f, bw1 = 0.f;
    float d01a = 0.f, d01b = 0.f;
    float aP = 0.f, bP = 0.f, aQ = 0.f, bQ = 0.f;
    float aR = 0.f, bR = 0.f, aS = 0.f, bS = 0.f;
    float selfmag = 0.f, t1s = 0.f, t2s = 0.f;
#pragma unroll
    for (int i = 0; i < 16; ++i) {
        float x0 = xr[i];
        float a  = xr[16 + 2 * i];
        float b  = xr[17 + 2 * i];
        d00     += x0 * w_n00[i];
        selfmag += x0 * w_self0[i];
        d01a    += x0 * w_n01[i * 2 + 0];
        d01b    += x0 * w_n01[i * 2 + 1];
        float w0 = w_n10[i * 2 + 0], w1 = w_n10[i * 2 + 1];
        aw0 += a * w0;  bw0 += b * w0;
        aw1 += a * w1;  bw1 += b * w1;
        float p = w_n11[i * 4 + 0], q = w_n11[i * 4 + 1];
        float r = w_n11[i * 4 + 2], s = w_n11[i * 4 + 3];
        aP += a * p;  bP += b * p;
        aQ += a * q;  bQ += b * q;
        aR += a * r;  bR += b * r;
        aS += a * s;  bS += b * s;
        float sa_ = w_self11[i * 2 + 0], sb_ = w_self11[i * 2 + 1];
        t1s += a * sa_ - b * sb_;
        t2s += b * sa_ + a * sb_;
    }
    uint4 w0, w1;
    w0.x = pack2(d00, aw0);  w0.y = pack2(bw0, aw1);
    w0.z = pack2(bw1, d01a); w0.w = pack2(d01b, aP);
    w1.x = pack2(bP, aQ);    w1.y = pack2(bQ, aR);
    w1.z = pack2(bR, aS);    w1.w = pack2(bS, 0.f);
    uint4* tp = (uint4*)(table + (size_t)v * 8);
    tp[0] = w0;  tp[1] = w1;
    float* sf = selfbuf + (size_t)v * 4;
    sf[0] = selfmag; sf[1] = t1s; sf[2] = t2s; sf[3] = 0.f;
}

// K2: per-chunk LDS tuple-sort + compute + write into the bin's global
// region reserved via one atomicAdd per (chunk,bin). Atomic issued right
// after the histogram so its ~700cy latency hides under the shfl-scan.
__global__ __launch_bounds__(BIGT)
void scatter_kernel(const int* __restrict__ src,
                    const int* __restrict__ dst,
                    const float* __restrict__ angles,
                    const float* __restrict__ transporters,
                    const uint32* __restrict__ table,
                    int* __restrict__ fill,
                    uint2* __restrict__ payload,
                    int E, int NB) {
    __shared__ int cnt_l[MAXNB];
    __shared__ int exoff_l[MAXNB];
    __shared__ int slot_l[MAXNB];
    __shared__ int wsum[16];
    __shared__ uint32 tw_src[CHUNK];
    __shared__ uint32 tw_ang[CHUNK];
    __shared__ uint32 tw_tr[CHUNK];
    __shared__ unsigned short tw_bin[CHUNK];

    int b = blockIdx.x;
    int lo = b * CHUNK;
    int hi = min(E, lo + CHUNK);
    int nloc = hi - lo;
    int tid = threadIdx.x;
    int lane = tid & 63;
    int wv = tid >> 6;

    for (int i = tid; i < NB; i += BIGT) cnt_l[i] = 0;
    __syncthreads();

    // pass1: chunk histogram (dst stays L1-warm for pass1b)
    for (int e = lo + tid; e < hi; e += BIGT)
        atomicAdd(&cnt_l[dst[e] >> VB_SHIFT], 1);
    __syncthreads();

    // reserve global bin space NOW (latency overlaps the scan below)
    int c = (tid < NB) ? cnt_l[tid] : 0;
    int rsv = 0;
    if (tid < NB && c > 0) rsv = atomicAdd(&fill[tid], c);

    // exclusive scan of chunk bin counts -> local sort offsets
    int incl = c;
#pragma unroll
    for (int d = 1; d < 64; d <<= 1) {
        int n = __shfl_up(incl, d);
        if (lane >= d) incl += n;
    }
    if (lane == 63) wsum[wv] = incl;
    __syncthreads();
    if (tid < 16) {
        int wval = wsum[tid], winc = wval;
#pragma unroll
        for (int d = 1; d < 16; d <<= 1) {
            int n = __shfl_up(winc, d);
            if (lane >= d) winc += n;
        }
        wsum[tid] = winc - wval;
    }
    __syncthreads();
    if (tid < NB) {
        int ex = incl - c + wsum[wv];
        exoff_l[tid] = ex;
        cnt_l[tid] = ex;                             // cursor
        slot_l[tid] = (tid << CAP_SHIFT) + rsv;      // global run start
    }
    __syncthreads();

    // pass1b: coalesced reads; tuple -> bin-sorted LDS slot
    for (int e = lo + tid; e < hi; e += BIGT) {
        int d = dst[e];
        int bin = d >> VB_SHIFT;
        uint32 dl = (uint32)(d & (VB - 1));
        int pos = atomicAdd(&cnt_l[bin], 1);
        tw_src[pos] = (uint32)src[e] | (dl << 17);
        tw_ang[pos] = __float_as_uint(angles[e]);
        tw_tr[pos]  = __float_as_uint(transporters[e]);
        tw_bin[pos] = (unsigned short)bin;
    }
    __syncthreads();

    // pass2: compute in bin order, write contiguous bin-region runs
    for (int k = tid; k < nloc; k += BIGT) {
        int bin = (int)tw_bin[k];
        uint32 w0i = tw_src[k];
        int s  = (int)(w0i & 0x1FFFFu);
        int dl = (int)(w0i >> 17);
        float ang = __uint_as_float(tw_ang[k]);
        float trv = __uint_as_float(tw_tr[k]);
        // native trig: args in [0, 2pi), err ~1e-6 << bf16 payload err
        float st = __sinf(ang), ct = __cosf(ang);
        float sg = __sinf(trv), cg = __cosf(trv);
        float c2t = ct * ct - st * st;
        float s2t = 2.0f * st * ct;

        const uint4* tp = (const uint4*)(table + (size_t)s * 8);
        uint4 W0 = tp[0], W1 = tp[1];
        float d00 = bf_lo(W0.x), aw0 = bf_hi(W0.x);
        float bw0 = bf_lo(W0.y), aw1 = bf_hi(W0.y);
        float bw1 = bf_lo(W0.z), d01a = bf_hi(W0.z);
        float d01b = bf_lo(W0.w), aP = bf_hi(W0.w);
        float bP = bf_lo(W1.x), aQ = bf_hi(W1.x);
        float bQ = bf_lo(W1.y), aR = bf_hi(W1.y);
        float bR = bf_lo(W1.z), aS = bf_hi(W1.z);
        float bS = bf_lo(W1.w);

        float u1w0 = cg * aw0 - sg * bw0, u2w0 = sg * aw0 + cg * bw0;
        float u1w1 = cg * aw1 - sg * bw1, u2w1 = sg * aw1 + cg * bw1;
        float m0 = d00 + ct * u1w0 + st * u2w0 - st * u1w1 + ct * u2w1;

        float u1p = cg * aP - sg * bP, u2p = sg * aP + cg * bP;
        float u1q = cg * aQ - sg * bQ, u2q = sg * aQ + cg * bQ;
        float u1r = cg * aR - sg * bR, u2r = sg * aR + cg * bR;
        float u1s = cg * aS - sg * bS, u2s = sg * aS + cg * bS;

        float mv1 = d01a * ct - d01b * st
                  + u1p - u2q
                  + c2t * u1r + s2t * u2r
                  - (s2t * u1s - c2t * u2s);
        float mv2 = d01a * st + d01b * ct
                  + u2p + u1q
                  + s2t * u1r - c2t * u2r
                  + c2t * u1s + s2t * u2s;

        uint2 pl;
        pl.x = pack2(m0, mv1);
        pl.y = f2bf(mv2) | ((uint32)dl << 16);
        int g = slot_l[bin] + (k - exoff_l[bin]);
        if (g < ((bin + 1) << CAP_SHIFT))            // overflow clamp
            payload[g] = pl;
    }
}

// K3: one block per bin. Dense contiguous read of payload[bin<<13 ..
// +fill[bin]); no run decoding, no validity branch; TWO packed u64
// fixed-point LDS atomics per edge (ds_add_u64); fused finalize.
__global__ __launch_bounds__(BIGT)
void bucket_kernel(const uint2* __restrict__ payload,
                   const int* __restrict__ fill,
                   const float* __restrict__ selfbuf,
                   const float* __restrict__ e1,
                   const float* __restrict__ e2,
                   float* __restrict__ out,
                   int V) {
    __shared__ uint64 acc[8][VB * 2];    // 32KB, wave-pair w=tid>>7 owns copy
    int bin = blockIdx.x;
    int tid = threadIdx.x;
    for (int i = tid; i < 8 * VB * 2; i += BIGT) ((uint64*)acc)[i] = 0ULL;
    __syncthreads();

    int n = min(fill[bin], CAP);
    const uint2* pp = payload + ((size_t)bin << CAP_SHIFT);
    uint64* myacc = acc[tid >> 7];
    for (int k = tid; k < n; k += BIGT) {
        uint2 pl = pp[k];
        float m0  = bf_lo(pl.x);
        float mv1 = bf_hi(pl.x);
        float mv2 = bf_lo(pl.y);
        int dl = (int)(pl.y >> 16);
        int m0f  = __float2int_rn(m0  * FIXS);
        int mv1f = __float2int_rn(mv1 * FIXS);
        int mv2f = __float2int_rn(mv2 * FIXS);
        uint64 pa = (uint64)(uint32)(m0f + BIASI)
                  | ((uint64)(uint32)mv1f << 32);
        uint64 pb = (uint64)(uint32)(mv2f + BIASI)
                  | (1ULL << 32);
        atomicAdd(&myacc[dl * 2 + 0], pa);
        atomicAdd(&myacc[dl * 2 + 1], pb);
    }
    __syncthreads();
    if (tid < VB) {
        int v = bin * VB + tid;
        if (v < V) {
            int cnt = 0, m0s = 0, mv1s = 0, mv2s = 0;
#pragma unroll
            for (int w = 0; w < 8; ++w) {
                uint64 a = acc[w][tid * 2 + 0];
                uint64 b = acc[w][tid * 2 + 1];
                uint32 nw = (uint32)(b >> 32);
                cnt  += (int)nw;
                m0s  += (int)((uint32)a - nw * (uint32)BIASI);
                mv1s += (int)(a >> 32);
                mv2s += (int)((uint32)b - nw * (uint32)BIASI);
            }
            float A0 = (float)m0s  * FIXSI;
            float A1 = (float)mv1s * FIXSI;
            float A2 = (float)mv2s * FIXSI;
            float inv = 1.0f / fmaxf((float)cnt, 1.0f);
            const float* sf = selfbuf + (size_t)v * 4;
            float mag = A0 * inv + sf[0];
            float t1  = A1 * inv + sf[1];
            float t2  = A2 * inv + sf[2];
            float scale = 2.0f / (1.0f + expf(-mag));
            float e1x = e1[v * 3 + 0], e1y = e1[v * 3 + 1], e1z = e1[v * 3 + 2];
            float e2x = e2[v * 3 + 0], e2y = e2[v * 3 + 1], e2z = e2[v * 3 + 2];
            out[v * 3 + 0] = (t1 * e1x + t2 * e2x) * scale;
            out[v * 3 + 1] = (t1 * e1y + t2 * e2y) * scale;
            out[v * 3 + 2] = (t1 * e1z + t2 * e2z) * scale;
        }
    }
}

extern "C" void kernel_launch(void* const* d_in, const int* in_sizes, int n_in,
                              void* d_out, int out_size, void* d_ws, size_t ws_size,
                              hipStream_t stream) {
    const float* x            = (const float*)d_in[0];
    const int*   edge_index   = (const int*)d_in[1];
    const float* angles       = (const float*)d_in[2];
    const float* transporters = (const float*)d_in[3];
    const float* e1           = (const float*)d_in[4];
    const float* e2           = (const float*)d_in[5];
    const float* w_self0      = (const float*)d_in[6];
    const float* w_n00        = (const float*)d_in[7];
    const float* w_n10        = (const float*)d_in[8];
    const float* w_self11     = (const float*)d_in[9];
    const float* w_n01        = (const float*)d_in[10];
    const float* w_n11        = (const float*)d_in[11];
    float* out = (float*)d_out;

    int V = in_sizes[0] / 48;
    int E = in_sizes[2];
    const int* src = edge_index;
    const int* dst = edge_index + E;

    int NB = (V + VB - 1) / VB;              // 391
    int nchunk = (E + CHUNK - 1) / CHUNK;    // 512

    char* p = (char*)d_ws;
    int* fill      = (int*)p;     p += (size_t)MAXNB * 4;
    uint32* table  = (uint32*)p;  p += (size_t)V * 8 * 4;         // 3.2MB
    float* selfbuf = (float*)p;   p += (size_t)V * 4 * 4;         // 1.6MB
    p = (char*)(((uintptr_t)p + 63) & ~(uintptr_t)63);
    uint2* payload = (uint2*)p;   // MAXNB * CAP * 8B = 26.2MB

    int gv = (V + 255) / 256;                // 391

    precompute_kernel<<<gv, 256, 0, stream>>>(
        x, w_self0, w_n00, w_n10, w_self11, w_n01, w_n11,
        table, selfbuf, fill, V, NB);
    scatter_kernel<<<nchunk, BIGT, 0, stream>>>(src, dst, angles,
                                                transporters, table,
                                                fill, payload, E, NB);
    bucket_kernel<<<NB, BIGT, 0, stream>>>(payload, fill, selfbuf,
                                           e1, e2, out, V);
}